// Round 13
// baseline (1234.068 us; speedup 1.0000x reference)
//
#include <hip/hip_runtime.h>
#include <math.h>

#define N    111
#define NR   112      // padded row/col stride for Ag and Xs
#define NE   4000
#define KP   100
#define APs  104      // Ap col stride
#define CA   56
#define TS   116      // transposed-20-buffer row stride (breaks 32-bank pattern)
#define NT   512

// permuted row -> original node id. rows 0..54 LEFT, 55 = node82, 56..110 RIGHT, 111 pad
__device__ __constant__ int d_P2O[112] = {
  6,5,55,1,98,71,73,77,63,96,79,15,104,4,25,23,41,43,45,17,61,65,59,57,86,21,
  35,37,39,94,110,3,69,81,84,100,102,106,47,27,75,2,67,19,49,31,33,108,51,53,
  88,90,92,29,0,
  82,
  13,12,54,8,97,70,72,76,62,95,78,14,103,11,24,22,40,42,44,16,60,64,58,56,85,
  20,34,36,38,93,109,10,68,80,83,99,101,105,46,26,74,9,66,18,48,30,32,107,50,
  52,87,89,91,28,7,
  111};

// flat LDS float pool offsets (floats)
#define OFF_A 0        // Ag 112x112=12544 -> Ap 100x104 -> assS 111x56 (6216) + HcT 20x56 (@+6216)
#define OFF_B 12544    // Xs 111x112 (P3) -> {W2ts 2x1280 | Wg1t 400 @+2560} -> {TCt|Tx1t|Tx2t 3x2320} -> s2S 111x56
#define OFF_C 24976    // T64 112x64=7168 -> T20t 20x116=2320 -> Wcs 3x1120 (P16)
#define OFF_D 32144    // H1 112x64=7168 (P3: Wlds stage, row111=0) -> {H2 | H2g @ +2240}
#define FSZ   39312

__device__ __forceinline__ float lrelu(float h) { return h > 0.f ? h : 0.01f * h; }

// R11: capped unrolls killed spills. R12: 7-row blocking for P3/P16.
// R13: transpose all 20-wide operands (T20t/TCt/Tx1t/Tx2t [20][116], W2ts, Wg1t,
// HcT) so P5/P6/P8/P14/P15b/P18 inner loops are float4 x float4 contiguous dots:
// 2 LDS reads per 4 FMAs instead of 5 scalar reads + 5 addr ops.
__global__ __launch_bounds__(NT, 1)
void brain_fused(const float* __restrict__ features,
                 const float* __restrict__ edge_attr,
                 const int*   __restrict__ edge_index,
                 const float* __restrict__ Wl1, const float* __restrict__ bl1,
                 const float* __restrict__ Wr1, const float* __restrict__ br1,
                 const float* __restrict__ Wl2, const float* __restrict__ bl2,
                 const float* __restrict__ Wr2, const float* __restrict__ br2,
                 const float* __restrict__ Wg1, const float* __restrict__ bg1,
                 const float* __restrict__ Wrel, const float* __restrict__ brel,
                 const float* __restrict__ Wroot,
                 const float* __restrict__ Wc0, const float* __restrict__ Wc1,
                 const float* __restrict__ Wc2, const float* __restrict__ bc,
                 float* __restrict__ out)
{
    __shared__ __align__(16) float F[FSZ];
    __shared__ float disH[112], disG[112], disC[112], scoreS[112];
    __shared__ int o2rS[112], mapRank[112], permSh[KP], spSh[KP];

    float* Ag   = F + OFF_A;            // 112x112
    float* Ap   = F + OFF_A;            // 100x104
    float* assS = F + OFF_A;            // 111x56
    float* HcT  = F + OFF_A + 6216;     // 20x56 (transposed Hc)
    float* Xs   = F + OFF_B;            // 111x112 permuted rows, col111=0 (P3)
    float* W2ts = F + OFF_B;            // 2x(20x64) transposed W2 (P5)
    float* Wg1t = F + OFF_B + 2560;     // 20x20 transposed Wg1 (P7)
    float* TCt  = F + OFF_B;            // 20x116
    float* Tx1t = F + OFF_B + 2320;     // 20x116
    float* Tx2t = F + OFF_B + 4640;     // 20x116
    float* s2S  = F + OFF_B;            // 111x56 (after P16)
    float* T64  = F + OFF_C;            // 112x64
    float* T20t = F + OFF_C;            // 20x116 (layer2 & global staging, transposed)
    float* Wcs  = F + OFF_C;            // Wc0|Wc1|Wc2 3x1120 (P16)
    float* H1   = F + OFF_D;            // 112x64
    float* Wlds = F + OFF_D;            // 112x64 W1 stage during P3 (row111=0)
    float* H2   = F + OFF_D;            // 112x20 (row-major)
    float* H2g  = F + OFF_D + 2240;     // 112x20 (row-major)

    const int b    = blockIdx.x;
    const int tid  = threadIdx.x;
    const int lane = tid & 63;
    const int wv   = tid >> 6;          // 0..7
    const float* x = features + (size_t)b * (N * N);

    // ---- P0: zero Ag, T64; build orig->row map ----
    for (int o = tid; o < 12544; o += NT) Ag[o] = 0.f;
    for (int o = tid; o < 7168;  o += NT) T64[o] = 0.f;
    if (tid < 112) o2rS[d_P2O[tid]] = tid;
    __syncthreads();

    // ---- P1a: scatter edges into Ag[t,s] (permuted) ----
    #pragma unroll 4
    for (int e = tid; e < NE; e += NT) {
        int s = o2rS[edge_index[e]];
        int t = o2rS[edge_index[NE + e]];
        atomicAdd(&Ag[t * NR + s], edge_attr[(size_t)b * NE + e]);
    }
    __syncthreads();

    // ---- P1b: stage x, permuted rows, stride 112, col111=0 ----
    #pragma unroll 4
    for (int o = tid; o < N * NR; o += NT) {
        int r = o / NR, cc = o % NR;
        Xs[o] = (cc < N) ? x[d_P2O[r] * N + cc] : 0.f;
    }
    __syncthreads();

    // ---- P2: degrees (wave/row, butterfly) ----
    #pragma unroll 1
    for (int k = 0; k < 14; ++k) {
        int r = wv + 8 * k;
        if (r >= 112) continue;
        if (r == 111) { if (lane == 0) { disH[111] = 0.f; disG[111] = 0.f; } continue; }
        float a0 = Ag[r * NR + lane];
        float a1 = (lane < 48) ? Ag[r * NR + 64 + lane] : 0.f;
        float sG = a0 + a1;
        float sH;
        if (r < 55)       sH = (lane < 55) ? a0 : 0.f;
        else if (r >= 56) sH = ((lane >= 56) ? a0 : 0.f) + ((lane < 47) ? a1 : 0.f);
        else              sH = 0.f;
        #pragma unroll
        for (int m = 1; m < 64; m <<= 1) {
            sG += __shfl_xor(sG, m);
            sH += __shfl_xor(sH, m);
        }
        if (lane == 0) {
            disG[r] = 1.f / sqrtf(sG + 1.f);
            disH[r] = (r == 55) ? 0.f : 1.f / sqrtf(sH + 1.f);
        }
    }
    __syncthreads();

    // ---- P3: T64 = disH .* (x @ W1hemi), 7-row register blocking ----
    #pragma unroll 1
    for (int half = 0; half < 2; ++half) {
        const float* W = (half == 0) ? Wl1 : Wr1;
        __syncthreads();
        #pragma unroll 4
        for (int o = tid; o < 1792; o += NT) {         // 112x16 float4; row111=0
            float4 v = make_float4(0.f, 0.f, 0.f, 0.f);
            if (o < 1776) v = ((const float4*)W)[o];
            ((float4*)Wlds)[o] = v;
        }
        __syncthreads();
        const int rlim  = (half == 0) ? 55 : 111;
        const int rbase = (half == 0) ? wv * 7 : 56 + wv * 7;
        float acc[7] = {0,0,0,0,0,0,0};
        int rr[7];
        #pragma unroll
        for (int u = 0; u < 7; ++u) { int r = rbase + u; rr[u] = (r < rlim) ? r : (rlim - 1); }
        #pragma unroll 1
        for (int j4 = 0; j4 < 28; ++j4) {
            float w0 = Wlds[(4 * j4 + 0) * 64 + lane];
            float w1 = Wlds[(4 * j4 + 1) * 64 + lane];
            float w2 = Wlds[(4 * j4 + 2) * 64 + lane];
            float w3 = Wlds[(4 * j4 + 3) * 64 + lane];
            #pragma unroll
            for (int u = 0; u < 7; ++u) {
                const float4 xv = *(const float4*)&Xs[rr[u] * NR + 4 * j4];
                acc[u] += xv.x * w0 + xv.y * w1 + xv.z * w2 + xv.w * w3;
            }
        }
        #pragma unroll
        for (int u = 0; u < 7; ++u) {
            int r = rbase + u;
            if (r < rlim) T64[r * 64 + lane] = disH[r] * acc[u];
        }
    }
    __syncthreads();

    // ---- P4 prologue: stage W2 TRANSPOSED into W2ts (Xs dead); re-zero H1 row 55 ----
    #pragma unroll 4
    for (int o = tid; o < 2560; o += NT) {
        int sel = o / 1280, rem = o - sel * 1280;
        int c = rem >> 6, k = rem & 63;
        const float* src = sel ? Wr2 : Wl2;
        W2ts[o] = src[k * 20 + c];
    }
    if (tid < 64) H1[55 * 64 + tid] = 0.f;
    __syncthreads();

    // ---- P4: H1 = lrelu(disH*(Ag_block @ T64 + self) + b1) ----
    #pragma unroll 1
    for (int half = 0; half < 2; ++half) {
        const int  rbase = half == 0 ? wv * 7 : 56 + wv * 7;
        const int  rlim  = half == 0 ? 55 : 111;
        const int  jb    = half == 0 ? 0 : 56;
        const float* bb  = half == 0 ? bl1 : br1;
        float acc[7] = {0,0,0,0,0,0,0};
        int rr[7];
        #pragma unroll
        for (int u = 0; u < 7; ++u) { int r = rbase + u; rr[u] = (r < rlim) ? r : (rlim - 1); }
        #pragma unroll 2
        for (int j4 = 0; j4 < 14; ++j4) {
            float t0 = T64[(jb + 4 * j4 + 0) * 64 + lane];
            float t1 = T64[(jb + 4 * j4 + 1) * 64 + lane];
            float t2 = T64[(jb + 4 * j4 + 2) * 64 + lane];
            float t3 = T64[(jb + 4 * j4 + 3) * 64 + lane];
            #pragma unroll
            for (int u = 0; u < 7; ++u) {
                const float4 a4 = *(const float4*)&Ag[rr[u] * NR + jb + 4 * j4];
                acc[u] += a4.x * t0 + a4.y * t1 + a4.z * t2 + a4.w * t3;
            }
        }
        float bv = bb[lane];
        #pragma unroll
        for (int u = 0; u < 7; ++u) {
            int r = rbase + u;
            if (r < rlim && r != 55)
                H1[r * 64 + lane] = lrelu(disH[r] * (acc[u] + T64[r * 64 + lane]) + bv);
        }
    }
    __syncthreads();

    // ---- P5: T20t[c][i] = disH[i]*(H1 row i . W2ts row c)  (float4 x float4)
    //      + stage Wg1 transposed. T64 dead now (T20t overwrites its head). ----
    #pragma unroll 2
    for (int o = tid; o < 400; o += NT) {
        int c = o / 20, k = o % 20;
        Wg1t[c * 20 + k] = Wg1[k * 20 + c];
    }
    for (int o = tid; o < 2240; o += NT) {
        int i = o / 20, c = o % 20;
        float r = 0.f;
        if (i < N) {
            const float4* h4 = (const float4*)(H1 + i * 64);
            const float4* w4 = (const float4*)(W2ts + ((i < 56) ? 0 : 1280) + c * 64);
            float acc = 0.f;
            #pragma unroll 4
            for (int k4 = 0; k4 < 16; ++k4) {
                float4 h = h4[k4], w = w4[k4];
                acc += h.x * w.x + h.y * w.y + h.z * w.z + h.w * w.w;
            }
            r = disH[i] * acc;
        }
        T20t[c * TS + i] = r;
    }
    __syncthreads();

    // ---- P6: H2[i][c] = lrelu(disH*(Ag_block row i . T20t row c + self) + b2) ----
    for (int o = tid; o < 2220; o += NT) {
        int i = o / 20, c = o % 20;
        if (i == 55) { H2[o] = 0.f; continue; }
        int jb = (i < 56) ? 0 : 56;
        const float4* a4p = (const float4*)(Ag + i * NR + jb);
        const float4* t4p = (const float4*)(T20t + c * TS + jb);
        float acc = 0.f;
        #pragma unroll 2
        for (int j4 = 0; j4 < 14; ++j4) {
            float4 a = a4p[j4], t = t4p[j4];
            acc += a.x * t.x + a.y * t.y + a.z * t.z + a.w * t.w;
        }
        float bv = (i < 56) ? bl2[c] : br2[c];
        H2[o] = lrelu(disH[i] * (acc + T20t[c * TS + i]) + bv);
    }
    __syncthreads();

    // ---- P7: T20t[c][i] = disG[i]*(H2 row i . Wg1t row c)  (5 float4 quads) ----
    for (int o = tid; o < 2240; o += NT) {
        int i = o / 20, c = o % 20;
        float r = 0.f;
        if (i < N) {
            const float4* h4 = (const float4*)(H2 + i * 20);
            const float4* w4 = (const float4*)(Wg1t + c * 20);
            float acc = 0.f;
            #pragma unroll 2
            for (int k4 = 0; k4 < 5; ++k4) {
                float4 h = h4[k4], w = w4[k4];
                acc += h.x * w.x + h.y * w.y + h.z * w.z + h.w * w.w;
            }
            r = disG[i] * acc;
        }
        T20t[c * TS + i] = r;
    }
    __syncthreads();

    // ---- P8: H2g[i][c] = lrelu(disG*(Ag row i . T20t row c + self) + bg1) ----
    for (int o = tid; o < 2220; o += NT) {
        int i = o / 20, c = o % 20;
        const float4* a4p = (const float4*)(Ag + i * NR);
        const float4* t4p = (const float4*)(T20t + c * TS);
        float acc = 0.f;
        #pragma unroll 2
        for (int j4 = 0; j4 < 28; ++j4) {
            float4 a = a4p[j4], t = t4p[j4];
            acc += a.x * t.x + a.y * t.y + a.z * t.z + a.w * t.w;
        }
        H2g[o] = lrelu(disG[i] * (acc + T20t[c * TS + i]) + bg1[c]);
    }
    __syncthreads();

    // ---- P9a: u = H2g.Wrel ; v = H2g.Wroot ----
    if (tid < 112) {
        if (tid == 111) { disC[111] = 0.f; scoreS[111] = 0.f; }
        else {
            float uu = 0.f, vv = 0.f;
            #pragma unroll 4
            for (int c = 0; c < 20; ++c) {
                float h = H2g[tid * 20 + c];
                uu += h * Wrel[c];
                vv += h * Wroot[c];
            }
            disC[tid] = uu; scoreS[tid] = vv;
        }
    }
    __syncthreads();

    // ---- P9b: score[i] = tanh(Ag row i . u + v[i] + brel)  (wave/row) ----
    {
        float brel0 = brel[0];
        #pragma unroll 1
        for (int k = 0; k < 14; ++k) {
            int r = wv + 8 * k;
            if (r >= N) continue;
            float p = Ag[r * NR + lane] * disC[lane];
            if (lane < 48) p += Ag[r * NR + 64 + lane] * disC[64 + lane];
            #pragma unroll
            for (int m = 1; m < 64; m <<= 1) p += __shfl_xor(p, m);
            if (lane == 0) scoreS[r] = tanhf(p + scoreS[r] + brel0);
        }
    }
    __syncthreads();

    // ---- P10: rank, perm, sp ; zero Ap ----
    if (tid < N) {
        float si = scoreS[tid];
        int oi = d_P2O[tid];
        int r = 0;
        #pragma unroll 4
        for (int j = 0; j < N; ++j) {
            float sj = scoreS[j];
            r += (sj > si || (sj == si && d_P2O[j] < oi)) ? 1 : 0;
        }
        mapRank[tid] = (r < KP) ? r : -1;
        if (r < KP) permSh[r] = tid;
    }
    if (tid == N) mapRank[111] = -1;
    for (int o = tid; o < KP * APs; o += NT) Ap[o] = 0.f;   // Ag dead after P9b
    __syncthreads();
    if (tid < N && mapRank[tid] >= 0) {
        int oi = d_P2O[tid], pos = 0;
        #pragma unroll 4
        for (int j = 0; j < N; ++j) pos += (mapRank[j] >= 0 && d_P2O[j] < oi) ? 1 : 0;
        spSh[pos] = tid;
    }
    __syncthreads();
    // ---- P11: scatter filtered adjacency (rank space) ----
    #pragma unroll 4
    for (int e = tid; e < NE; e += NT) {
        int sr = o2rS[edge_index[e]];
        int tr = o2rS[edge_index[NE + e]];
        int ms = mapRank[sr], mt = mapRank[tr];
        if (ms >= 0 && mt >= 0 && ms != mt) atomicAdd(&Ap[mt * APs + ms], 1.f);
    }
    __syncthreads();

    // ---- P12: disC from column sums of Ap ----
    if (tid < APs) {
        if (tid >= KP) disC[tid] = 0.f;
        else {
            float d = 0.f;
            #pragma unroll 4
            for (int a = 0; a < KP; ++a) d += Ap[a * APs + tid];
            disC[tid] = (d > 0.f) ? 1.f / sqrtf(d) : 0.f;
        }
    }
    __syncthreads();

    // ---- P13: TCt[c][j] = disC[j]*h2[node j][c]  (W2ts/Wg1t dead); stage Wcs ----
    for (int o = tid; o < APs * 20; o += NT) {
        int bq = o / 20, c = o % 20;
        TCt[c * TS + bq] = disC[bq] * H2g[o2rS[bq] * 20 + c];
    }
    #pragma unroll 4
    for (int o = tid; o < 1120; o += NT) {
        Wcs[o] = Wc0[o]; Wcs[1120 + o] = Wc1[o]; Wcs[2240 + o] = Wc2[o];
    }
    __syncthreads();

    // ---- P14: Tx1t[c][a] = -disC[a]*(Ap row a . TCt row c) ----
    for (int o = tid; o < KP * 20; o += NT) {
        int a = o / 20, c = o % 20;
        const float4* a4p = (const float4*)(Ap + a * APs);
        const float4* t4p = (const float4*)(TCt + c * TS);
        float acc = 0.f;
        #pragma unroll 2
        for (int j4 = 0; j4 < 26; ++j4) {
            float4 av = a4p[j4], tv = t4p[j4];
            acc += av.x * tv.x + av.y * tv.y + av.z * tv.z + av.w * tv.w;
        }
        Tx1t[c * TS + a] = -disC[a] * acc;
    }
    __syncthreads();
    // ---- P15a: TCt[c][a] = disC[a]*Tx1t[c][a]  (cols 100..103 stay 0 from P13) ----
    for (int o = tid; o < KP * 20; o += NT) {
        int a = o / 20, c = o % 20;
        TCt[c * TS + a] = disC[a] * Tx1t[c * TS + a];
    }
    __syncthreads();
    // ---- P15b: Tx2t[c][a] = -2*disC[a]*(Ap row a . TCt row c) - h2[node a][c] ----
    for (int o = tid; o < KP * 20; o += NT) {
        int a = o / 20, c = o % 20;
        const float4* a4p = (const float4*)(Ap + a * APs);
        const float4* t4p = (const float4*)(TCt + c * TS);
        float acc = 0.f;
        #pragma unroll 2
        for (int j4 = 0; j4 < 26; ++j4) {
            float4 av = a4p[j4], tv = t4p[j4];
            acc += av.x * tv.x + av.y * tv.y + av.z * tv.z + av.w * tv.w;
        }
        Tx2t[c * TS + a] = -2.f * disC[a] * acc - H2g[o2rS[a] * 20 + c];
    }
    __syncthreads();

    // ---- P16: assignment logits — 7-row blocking, lane=class. Tx via transposed rows. ----
    {
        float bcv = (lane < CA) ? bc[lane] : 0.f;
        #pragma unroll 1
        for (int pass = 0; pass < 2; ++pass) {
            const int base = wv * 14 + pass * 7;
            float acc[7] = {0,0,0,0,0,0,0};
            int ho[7], txc[7], in7[7];
            #pragma unroll
            for (int u = 0; u < 7; ++u) {
                int i = base + u;
                int ic = (i < N) ? i : (N - 1);
                ho[u]  = o2rS[ic] * 20;
                in7[u] = (ic < KP) ? 1 : 0;
                txc[u] = (ic < KP) ? ic : 0;
            }
            #pragma unroll 1
            for (int k = 0; k < 20; ++k) {
                float w0 = Wcs[k * CA + lane];
                float w1 = Wcs[1120 + k * CA + lane];
                float w2 = Wcs[2240 + k * CA + lane];
                #pragma unroll
                for (int u = 0; u < 7; ++u) {
                    float h  = H2g[ho[u] + k];                       // broadcast
                    float t1 = in7[u] ? Tx1t[k * TS + txc[u]] : 0.f; // broadcast
                    float t2 = in7[u] ? Tx2t[k * TS + txc[u]] : -h;  // broadcast
                    acc[u] += h * w0 + t1 * w1 + t2 * w2;
                }
            }
            #pragma unroll
            for (int u = 0; u < 7; ++u) {
                int i = base + u;
                if (i < N && lane < CA) assS[i * CA + lane] = acc[u] + bcv;
            }
        }
    }
    __syncthreads();

    // ---- P16b: double softmax per row (wave/row, butterfly). s2S clobbers Tx* (dead). ----
    #pragma unroll 1
    for (int k = 0; k < 14; ++k) {
        int r = wv + 8 * k;
        if (r >= N) continue;
        float v = (lane < CA) ? assS[r * CA + lane] : -3.4e38f;
        float m = v;
        #pragma unroll
        for (int s = 1; s < 64; s <<= 1) m = fmaxf(m, __shfl_xor(m, s));
        float e = (lane < CA) ? expf(v - m) : 0.f;
        float sum = e;
        #pragma unroll
        for (int s = 1; s < 64; s <<= 1) sum += __shfl_xor(sum, s);
        float p1 = e / sum;
        float m2 = (lane < CA) ? p1 : -3.4e38f;
        #pragma unroll
        for (int s = 1; s < 64; s <<= 1) m2 = fmaxf(m2, __shfl_xor(m2, s));
        float e2 = (lane < CA) ? expf(p1 - m2) : 0.f;
        float sum2 = e2;
        #pragma unroll
        for (int s = 1; s < 64; s <<= 1) sum2 += __shfl_xor(sum2, s);
        if (lane < CA) {
            assS[r * CA + lane] = p1;
            s2S[r * CA + lane]  = e2 / sum2;
        }
    }
    __syncthreads();

    // ---- P17: HcT[c][q] = sum_r s2[node r][q] * h2[r][c] ----
    for (int o = tid; o < CA * 20; o += NT) {
        int q = o / 20, c = o % 20;
        float acc = 0.f;
        #pragma unroll 4
        for (int r = 0; r < N; ++r) acc += s2S[d_P2O[r] * CA + q] * H2g[r * 20 + c];
        HcT[c * CA + q] = acc;
    }
    __syncthreads();

    // ---- P18: out = pooled + (assS row oi . HcT row c)  (float4 x float4) ----
    for (int o = tid; o < KP * 20; o += NT) {
        int k = o / 20, c = o % 20;
        int rp = permSh[k];
        float v = H2g[rp * 20 + c] * scoreS[rp];
        int oi = d_P2O[spSh[k]];
        if (oi < 110) {
            const float4* s4 = (const float4*)(assS + oi * CA);
            const float4* h4 = (const float4*)(HcT + c * CA);
            float acc = 0.f;
            #pragma unroll 2
            for (int q4 = 0; q4 < 14; ++q4) {
                float4 s = s4[q4], h = h4[q4];
                acc += s.x * h.x + s.y * h.y + s.z * h.z + s.w * h.w;
            }
            v += acc;
        }
        out[(size_t)b * (KP * 20) + o] = v;
    }
}

extern "C" void kernel_launch(void* const* d_in, const int* in_sizes, int n_in,
                              void* d_out, int out_size, void* d_ws, size_t ws_size,
                              hipStream_t stream) {
    const float* features   = (const float*)d_in[0];
    const float* edge_attr  = (const float*)d_in[1];
    // d_in[2] = adj (unused by reference)
    const int*   edge_index = (const int*)d_in[3];
    const float* Wl1 = (const float*)d_in[4];
    const float* bl1 = (const float*)d_in[5];
    const float* Wr1 = (const float*)d_in[6];
    const float* br1 = (const float*)d_in[7];
    const float* Wl2 = (const float*)d_in[8];
    const float* bl2 = (const float*)d_in[9];
    const float* Wr2 = (const float*)d_in[10];
    const float* br2 = (const float*)d_in[11];
    const float* Wg1 = (const float*)d_in[12];
    const float* bg1 = (const float*)d_in[13];
    const float* Wrel = (const float*)d_in[14];
    const float* brel = (const float*)d_in[15];
    const float* Wroot = (const float*)d_in[16];
    const float* Wc0 = (const float*)d_in[17];
    const float* Wc1 = (const float*)d_in[18];
    const float* Wc2 = (const float*)d_in[19];
    const float* bc  = (const float*)d_in[20];
    float* out = (float*)d_out;

    int B = in_sizes[0] / (N * N);
    brain_fused<<<dim3(B), dim3(NT), 0, stream>>>(
        features, edge_attr, edge_index,
        Wl1, bl1, Wr1, br1, Wl2, bl2, Wr2, br2, Wg1, bg1,
        Wrel, brel, Wroot, Wc0, Wc1, Wc2, bc, out);
}

// Round 14
// 941.762 us; speedup vs baseline: 1.3104x; 1.3104x over previous
//
#include <hip/hip_runtime.h>
#include <math.h>

#define N    111
#define NR   112      // padded row/col stride for Ag and Xs
#define NE   4000
#define KP   100
#define APs  104      // Ap col stride
#define CA   56
#define NT   1024     // 16 waves: 4 waves/SIMD (occupancy 24->47%). Safe now that
                      // R11's capped unrolls hold VGPR demand under the 64 budget
                      // hipcc pins for 1024-thr blocks. Spill tripwire: WRITE_SIZE.

// permuted row -> original node id. rows 0..54 LEFT, 55 = node82, 56..110 RIGHT, 111 pad
__device__ __constant__ int d_P2O[112] = {
  6,5,55,1,98,71,73,77,63,96,79,15,104,4,25,23,41,43,45,17,61,65,59,57,86,21,
  35,37,39,94,110,3,69,81,84,100,102,106,47,27,75,2,67,19,49,31,33,108,51,53,
  88,90,92,29,0,
  82,
  13,12,54,8,97,70,72,76,62,95,78,14,103,11,24,22,40,42,44,16,60,64,58,56,85,
  20,34,36,38,93,109,10,68,80,83,99,101,105,46,26,74,9,66,18,48,30,32,107,50,
  52,87,89,91,28,7,
  111};

// flat LDS float pool offsets (floats) — R12 layout (row-major 20-wide buffers)
#define OFF_A 0        // Ag 112x112=12544 -> Ap 100x104 -> assS 111x56 (6216) + HcS 56x20 (@+6216)
#define OFF_B 12544    // Xs 111x112 (P3) -> W2s 2x1280 -> {TC|Tx1|Tx2 3x2080} -> s2S 111x56
#define OFF_C 24976    // T64 112x64=7168 -> T20x 112x20=2240 -> Wcs 3x1120 (P16)
#define OFF_D 32144    // H1 112x64=7168 (P3: Wlds stage, row111=0) -> {H2 | H2g @ +2240}
#define FSZ   39312

__device__ __forceinline__ float lrelu(float h) { return h > 0.f ? h : 0.01f * h; }

// R11: capped unrolls -> no spills. R12: 7-row blocking P3/P16 (row-major, few
// conflicts). R13 transpose REVERTED (bank conflicts 8.5e6 -> 7.1e7, -4%).
// R14: NT=1024, 4-row blocking in P3/P4, single-pass P16.
__global__ __launch_bounds__(NT, 1)
void brain_fused(const float* __restrict__ features,
                 const float* __restrict__ edge_attr,
                 const int*   __restrict__ edge_index,
                 const float* __restrict__ Wl1, const float* __restrict__ bl1,
                 const float* __restrict__ Wr1, const float* __restrict__ br1,
                 const float* __restrict__ Wl2, const float* __restrict__ bl2,
                 const float* __restrict__ Wr2, const float* __restrict__ br2,
                 const float* __restrict__ Wg1, const float* __restrict__ bg1,
                 const float* __restrict__ Wrel, const float* __restrict__ brel,
                 const float* __restrict__ Wroot,
                 const float* __restrict__ Wc0, const float* __restrict__ Wc1,
                 const float* __restrict__ Wc2, const float* __restrict__ bc,
                 float* __restrict__ out)
{
    __shared__ __align__(16) float F[FSZ];
    __shared__ float disH[112], disG[112], disC[112], scoreS[112];
    __shared__ int o2rS[112], mapRank[112], permSh[KP], spSh[KP];

    float* Ag   = F + OFF_A;            // 112x112
    float* Ap   = F + OFF_A;            // 100x104
    float* assS = F + OFF_A;            // 111x56
    float* HcS  = F + OFF_A + 6216;     // 56x20
    float* Xs   = F + OFF_B;            // 111x112 permuted rows, col111=0 (P3)
    float* W2s  = F + OFF_B;            // Wl2|Wr2 (2x1280) during P5
    float* TC   = F + OFF_B;            // 104x20
    float* Tx1  = F + OFF_B + 2080;     // 100x20
    float* Tx2  = F + OFF_B + 4080;     // 100x20
    float* s2S  = F + OFF_B;            // 111x56 (after P16)
    float* T64  = F + OFF_C;            // 112x64
    float* T20x = F + OFF_C;            // 112x20
    float* Wcs  = F + OFF_C;            // Wc0|Wc1|Wc2 3x1120 (P16)
    float* H1   = F + OFF_D;            // 112x64
    float* Wlds = F + OFF_D;            // 112x64 W1 stage during P3 (row111=0)
    float* H2   = F + OFF_D;            // 112x20
    float* H2g  = F + OFF_D + 2240;     // 112x20

    const int b    = blockIdx.x;
    const int tid  = threadIdx.x;
    const int lane = tid & 63;
    const int wv   = tid >> 6;          // 0..15
    const float* x = features + (size_t)b * (N * N);

    // ---- P0: zero Ag, T64; build orig->row map ----
    for (int o = tid; o < 12544; o += NT) Ag[o] = 0.f;
    for (int o = tid; o < 7168;  o += NT) T64[o] = 0.f;
    if (tid < 112) o2rS[d_P2O[tid]] = tid;
    __syncthreads();

    // ---- P1a: scatter edges into Ag[t,s] (permuted) ----
    #pragma unroll 2
    for (int e = tid; e < NE; e += NT) {
        int s = o2rS[edge_index[e]];
        int t = o2rS[edge_index[NE + e]];
        atomicAdd(&Ag[t * NR + s], edge_attr[(size_t)b * NE + e]);
    }
    __syncthreads();

    // ---- P1b: stage x, permuted rows, stride 112, col111=0 ----
    #pragma unroll 2
    for (int o = tid; o < N * NR; o += NT) {
        int r = o / NR, cc = o % NR;
        Xs[o] = (cc < N) ? x[d_P2O[r] * N + cc] : 0.f;
    }
    __syncthreads();

    // ---- P2: degrees (wave/row over 16 waves, butterfly) ----
    #pragma unroll 1
    for (int k = 0; k < 7; ++k) {
        int r = wv + 16 * k;
        if (r >= 112) continue;
        if (r == 111) { if (lane == 0) { disH[111] = 0.f; disG[111] = 0.f; } continue; }
        float a0 = Ag[r * NR + lane];
        float a1 = (lane < 48) ? Ag[r * NR + 64 + lane] : 0.f;
        float sG = a0 + a1;
        float sH;
        if (r < 55)       sH = (lane < 55) ? a0 : 0.f;
        else if (r >= 56) sH = ((lane >= 56) ? a0 : 0.f) + ((lane < 47) ? a1 : 0.f);
        else              sH = 0.f;
        #pragma unroll
        for (int m = 1; m < 64; m <<= 1) {
            sG += __shfl_xor(sG, m);
            sH += __shfl_xor(sH, m);
        }
        if (lane == 0) {
            disG[r] = 1.f / sqrtf(sG + 1.f);
            disH[r] = (r == 55) ? 0.f : 1.f / sqrtf(sH + 1.f);
        }
    }
    __syncthreads();

    // ---- P3: T64 = disH .* (x @ W1hemi), 4-row register blocking (16 waves) ----
    #pragma unroll 1
    for (int half = 0; half < 2; ++half) {
        const float* W = (half == 0) ? Wl1 : Wr1;
        __syncthreads();   // prior compute done before re-staging Wlds
        #pragma unroll 2
        for (int o = tid; o < 1792; o += NT) {         // 112x16 float4; row111=0
            float4 v = make_float4(0.f, 0.f, 0.f, 0.f);
            if (o < 1776) v = ((const float4*)W)[o];
            ((float4*)Wlds)[o] = v;
        }
        __syncthreads();
        const int rlim  = (half == 0) ? 55 : 111;
        const int rbase = (half == 0) ? wv * 4 : 56 + wv * 4;
        float acc[4] = {0,0,0,0};
        int rr[4];
        #pragma unroll
        for (int u = 0; u < 4; ++u) { int r = rbase + u; rr[u] = (r < rlim) ? r : (rlim - 1); }
        #pragma unroll 1
        for (int j4 = 0; j4 < 28; ++j4) {
            float w0 = Wlds[(4 * j4 + 0) * 64 + lane];
            float w1 = Wlds[(4 * j4 + 1) * 64 + lane];
            float w2 = Wlds[(4 * j4 + 2) * 64 + lane];
            float w3 = Wlds[(4 * j4 + 3) * 64 + lane];
            #pragma unroll
            for (int u = 0; u < 4; ++u) {
                const float4 xv = *(const float4*)&Xs[rr[u] * NR + 4 * j4];  // broadcast
                acc[u] += xv.x * w0 + xv.y * w1 + xv.z * w2 + xv.w * w3;
            }
        }
        #pragma unroll
        for (int u = 0; u < 4; ++u) {
            int r = rbase + u;
            if (r < rlim) T64[r * 64 + lane] = disH[r] * acc[u];
        }
    }
    __syncthreads();

    // ---- P4 prologue: stage Wl2|Wr2 (Xs dead); re-zero H1 row 55 (Wlds clobber); fence ----
    #pragma unroll 2
    for (int o = tid; o < 1280; o += NT) { W2s[o] = Wl2[o]; W2s[1280 + o] = Wr2[o]; }
    if (tid < 64) H1[55 * 64 + tid] = 0.f;
    __syncthreads();

    // ---- P4: H1 = lrelu(disH*(Ag_block @ T64 + self) + b1), 4-row blocking ----
    #pragma unroll 1
    for (int half = 0; half < 2; ++half) {
        const int  rbase = half == 0 ? wv * 4 : 56 + wv * 4;
        const int  rlim  = half == 0 ? 55 : 111;
        const int  jb    = half == 0 ? 0 : 56;
        const float* bb  = half == 0 ? bl1 : br1;
        float acc[4] = {0,0,0,0};
        int rr[4];
        #pragma unroll
        for (int u = 0; u < 4; ++u) { int r = rbase + u; rr[u] = (r < rlim) ? r : (rlim - 1); }
        #pragma unroll 2
        for (int j4 = 0; j4 < 14; ++j4) {
            float t0 = T64[(jb + 4 * j4 + 0) * 64 + lane];
            float t1 = T64[(jb + 4 * j4 + 1) * 64 + lane];
            float t2 = T64[(jb + 4 * j4 + 2) * 64 + lane];
            float t3 = T64[(jb + 4 * j4 + 3) * 64 + lane];
            #pragma unroll
            for (int u = 0; u < 4; ++u) {
                const float4 a4 = *(const float4*)&Ag[rr[u] * NR + jb + 4 * j4];
                acc[u] += a4.x * t0 + a4.y * t1 + a4.z * t2 + a4.w * t3;
            }
        }
        float bv = bb[lane];
        #pragma unroll
        for (int u = 0; u < 4; ++u) {
            int r = rbase + u;
            if (r < rlim && r != 55)
                H1[r * 64 + lane] = lrelu(disH[r] * (acc[u] + T64[r * 64 + lane]) + bv);
        }
    }
    __syncthreads();

    // ---- P5: T20x = disH .* (H1 @ W2hemi)   (capped k4 unroll) ----
    for (int o = tid; o < 2240; o += NT) {
        int i = o / 20, c = o % 20;
        if (i == 111) { T20x[o] = 0.f; continue; }
        const float* W2 = (i < 56) ? W2s : (W2s + 1280);
        const float4* h4 = (const float4*)(H1 + i * 64);
        float acc = 0.f;
        #pragma unroll 4
        for (int k4 = 0; k4 < 16; ++k4) {
            float4 h = h4[k4];
            acc += h.x * W2[(4 * k4 + 0) * 20 + c]
                 + h.y * W2[(4 * k4 + 1) * 20 + c]
                 + h.z * W2[(4 * k4 + 2) * 20 + c]
                 + h.w * W2[(4 * k4 + 3) * 20 + c];
        }
        T20x[o] = disH[i] * acc;
    }
    __syncthreads();

    // ---- P6: H2 = lrelu(disH*(Ag_block @ T20x + self) + b2) ----
    for (int o = tid; o < 2220; o += NT) {
        int i = o / 20, c = o % 20;
        if (i == 55) { H2[o] = 0.f; continue; }
        int jb = (i < 56) ? 0 : 56;
        float acc = 0.f;
        #pragma unroll 2
        for (int j4 = 0; j4 < 14; ++j4) {
            const float4 a4 = *(const float4*)&Ag[i * NR + jb + 4 * j4];
            acc += a4.x * T20x[(jb + 4 * j4 + 0) * 20 + c]
                 + a4.y * T20x[(jb + 4 * j4 + 1) * 20 + c]
                 + a4.z * T20x[(jb + 4 * j4 + 2) * 20 + c]
                 + a4.w * T20x[(jb + 4 * j4 + 3) * 20 + c];
        }
        float bv = (i < 56) ? bl2[c] : br2[c];
        H2[o] = lrelu(disH[i] * (acc + T20x[i * 20 + c]) + bv);
    }
    __syncthreads();

    // ---- P7: T20g = disG .* (H2 @ Wg1) ----
    for (int o = tid; o < 2240; o += NT) {
        int i = o / 20, c = o % 20;
        if (i == 111) { T20x[o] = 0.f; continue; }
        float acc = 0.f;
        #pragma unroll 4
        for (int k = 0; k < 20; ++k) acc += H2[i * 20 + k] * Wg1[k * 20 + c];
        T20x[o] = disG[i] * acc;
    }
    __syncthreads();

    // ---- P8: H2g = lrelu(disG*(Ag @ T20g + self) + bg1) ----
    for (int o = tid; o < 2220; o += NT) {
        int i = o / 20, c = o % 20;
        float acc = 0.f;
        #pragma unroll 2
        for (int j4 = 0; j4 < 28; ++j4) {
            const float4 a4 = *(const float4*)&Ag[i * NR + 4 * j4];
            acc += a4.x * T20x[(4 * j4 + 0) * 20 + c]
                 + a4.y * T20x[(4 * j4 + 1) * 20 + c]
                 + a4.z * T20x[(4 * j4 + 2) * 20 + c]
                 + a4.w * T20x[(4 * j4 + 3) * 20 + c];
        }
        H2g[o] = lrelu(disG[i] * (acc + T20x[i * 20 + c]) + bg1[c]);
    }
    __syncthreads();

    // ---- P9a: u = H2g.Wrel ; v = H2g.Wroot ----
    if (tid < 112) {
        if (tid == 111) { disC[111] = 0.f; scoreS[111] = 0.f; }
        else {
            float uu = 0.f, vv = 0.f;
            #pragma unroll 4
            for (int c = 0; c < 20; ++c) {
                float h = H2g[tid * 20 + c];
                uu += h * Wrel[c];
                vv += h * Wroot[c];
            }
            disC[tid] = uu; scoreS[tid] = vv;
        }
    }
    __syncthreads();

    // ---- P9b: score[i] = tanh(Ag row i . u + v[i] + brel)  (wave/row, 16 waves) ----
    {
        float brel0 = brel[0];
        #pragma unroll 1
        for (int k = 0; k < 7; ++k) {
            int r = wv + 16 * k;
            if (r >= N) continue;
            float p = Ag[r * NR + lane] * disC[lane];
            if (lane < 48) p += Ag[r * NR + 64 + lane] * disC[64 + lane];
            #pragma unroll
            for (int m = 1; m < 64; m <<= 1) p += __shfl_xor(p, m);
            if (lane == 0) scoreS[r] = tanhf(p + scoreS[r] + brel0);
        }
    }
    __syncthreads();

    // ---- P10: rank, perm, sp ; zero Ap ----
    if (tid < N) {
        float si = scoreS[tid];
        int oi = d_P2O[tid];
        int r = 0;
        #pragma unroll 4
        for (int j = 0; j < N; ++j) {
            float sj = scoreS[j];
            r += (sj > si || (sj == si && d_P2O[j] < oi)) ? 1 : 0;
        }
        mapRank[tid] = (r < KP) ? r : -1;
        if (r < KP) permSh[r] = tid;
    }
    if (tid == N) mapRank[111] = -1;
    for (int o = tid; o < KP * APs; o += NT) Ap[o] = 0.f;
    __syncthreads();
    if (tid < N && mapRank[tid] >= 0) {
        int oi = d_P2O[tid], pos = 0;
        #pragma unroll 4
        for (int j = 0; j < N; ++j) pos += (mapRank[j] >= 0 && d_P2O[j] < oi) ? 1 : 0;
        spSh[pos] = tid;
    }
    __syncthreads();
    // ---- P11: scatter filtered adjacency (rank space) ----
    #pragma unroll 2
    for (int e = tid; e < NE; e += NT) {
        int sr = o2rS[edge_index[e]];
        int tr = o2rS[edge_index[NE + e]];
        int ms = mapRank[sr], mt = mapRank[tr];
        if (ms >= 0 && mt >= 0 && ms != mt) atomicAdd(&Ap[mt * APs + ms], 1.f);
    }
    __syncthreads();

    // ---- P12: disC from column sums of Ap ----
    if (tid < APs) {
        if (tid >= KP) disC[tid] = 0.f;
        else {
            float d = 0.f;
            #pragma unroll 4
            for (int a = 0; a < KP; ++a) d += Ap[a * APs + tid];
            disC[tid] = (d > 0.f) ? 1.f / sqrtf(d) : 0.f;
        }
    }
    __syncthreads();

    // ---- P13: TC[b] = disC[b]*h2[node b]; stage Wcs ----
    for (int o = tid; o < APs * 20; o += NT) {
        int bq = o / 20, c = o % 20;
        TC[o] = disC[bq] * H2g[o2rS[bq] * 20 + c];
    }
    #pragma unroll 2
    for (int o = tid; o < 1120; o += NT) {
        Wcs[o] = Wc0[o]; Wcs[1120 + o] = Wc1[o]; Wcs[2240 + o] = Wc2[o];
    }
    __syncthreads();

    // ---- P14: Tx1[a] = -disC[a] * (Ap @ TC)[a] ----
    for (int o = tid; o < KP * 20; o += NT) {
        int a = o / 20, c = o % 20;
        float acc = 0.f;
        #pragma unroll 2
        for (int j4 = 0; j4 < 26; ++j4) {
            const float4 a4 = *(const float4*)&Ap[a * APs + 4 * j4];
            acc += a4.x * TC[(4 * j4 + 0) * 20 + c]
                 + a4.y * TC[(4 * j4 + 1) * 20 + c]
                 + a4.z * TC[(4 * j4 + 2) * 20 + c]
                 + a4.w * TC[(4 * j4 + 3) * 20 + c];
        }
        Tx1[o] = -disC[a] * acc;
    }
    __syncthreads();
    // ---- P15a: TC = disC .* Tx1 ----
    for (int o = tid; o < KP * 20; o += NT) TC[o] = disC[o / 20] * Tx1[o];
    __syncthreads();
    // ---- P15b: Tx2[a] = -2*disC[a]*(Ap@TC)[a] - h2[node a] ----
    for (int o = tid; o < KP * 20; o += NT) {
        int a = o / 20, c = o % 20;
        float acc = 0.f;
        #pragma unroll 2
        for (int j4 = 0; j4 < 26; ++j4) {
            const float4 a4 = *(const float4*)&Ap[a * APs + 4 * j4];
            acc += a4.x * TC[(4 * j4 + 0) * 20 + c]
                 + a4.y * TC[(4 * j4 + 1) * 20 + c]
                 + a4.z * TC[(4 * j4 + 2) * 20 + c]
                 + a4.w * TC[(4 * j4 + 3) * 20 + c];
        }
        Tx2[o] = -2.f * disC[a] * acc - H2g[o2rS[a] * 20 + c];
    }
    __syncthreads();

    // ---- P16: assignment logits — 7-row blocking, single pass (16 waves x 7 = 112) ----
    {
        float bcv = (lane < CA) ? bc[lane] : 0.f;
        const int base = wv * 7;
        float acc[7] = {0,0,0,0,0,0,0};
        int ho[7], txo[7], in7[7];
        #pragma unroll
        for (int u = 0; u < 7; ++u) {
            int i = base + u;
            int ic = (i < N) ? i : (N - 1);
            ho[u]  = o2rS[ic] * 20;
            in7[u] = (ic < KP) ? 1 : 0;
            txo[u] = ((ic < KP) ? ic : 0) * 20;
        }
        #pragma unroll 1
        for (int k = 0; k < 20; ++k) {
            float w0 = Wcs[k * CA + lane];
            float w1 = Wcs[1120 + k * CA + lane];
            float w2 = Wcs[2240 + k * CA + lane];
            #pragma unroll
            for (int u = 0; u < 7; ++u) {
                float h  = H2g[ho[u] + k];                 // broadcast
                float t1 = in7[u] ? Tx1[txo[u] + k] : 0.f; // broadcast
                float t2 = in7[u] ? Tx2[txo[u] + k] : -h;  // broadcast
                acc[u] += h * w0 + t1 * w1 + t2 * w2;
            }
        }
        #pragma unroll
        for (int u = 0; u < 7; ++u) {
            int i = base + u;
            if (i < N && lane < CA) assS[i * CA + lane] = acc[u] + bcv;
        }
    }
    __syncthreads();

    // ---- P16b: double softmax per row (wave/row, 16 waves, butterfly) ----
    #pragma unroll 1
    for (int k = 0; k < 7; ++k) {
        int r = wv + 16 * k;
        if (r >= N) continue;
        float v = (lane < CA) ? assS[r * CA + lane] : -3.4e38f;
        float m = v;
        #pragma unroll
        for (int s = 1; s < 64; s <<= 1) m = fmaxf(m, __shfl_xor(m, s));
        float e = (lane < CA) ? expf(v - m) : 0.f;
        float sum = e;
        #pragma unroll
        for (int s = 1; s < 64; s <<= 1) sum += __shfl_xor(sum, s);
        float p1 = e / sum;
        float m2 = (lane < CA) ? p1 : -3.4e38f;
        #pragma unroll
        for (int s = 1; s < 64; s <<= 1) m2 = fmaxf(m2, __shfl_xor(m2, s));
        float e2 = (lane < CA) ? expf(p1 - m2) : 0.f;
        float sum2 = e2;
        #pragma unroll
        for (int s = 1; s < 64; s <<= 1) sum2 += __shfl_xor(sum2, s);
        if (lane < CA) {
            assS[r * CA + lane] = p1;
            s2S[r * CA + lane]  = e2 / sum2;
        }
    }
    __syncthreads();

    // ---- P17: Hc = s2^T @ h2 ----
    for (int o = tid; o < CA * 20; o += NT) {
        int q = o / 20, c = o % 20;
        float acc = 0.f;
        #pragma unroll 4
        for (int r = 0; r < N; ++r) acc += s2S[d_P2O[r] * CA + q] * H2g[r * 20 + c];
        HcS[o] = acc;
    }
    __syncthreads();

    // ---- P18: out = pooled + inter @ Hc ----
    for (int o = tid; o < KP * 20; o += NT) {
        int k = o / 20, c = o % 20;
        int rp = permSh[k];
        float v = H2g[rp * 20 + c] * scoreS[rp];
        int oi = d_P2O[spSh[k]];
        if (oi < 110) {
            float acc = 0.f;
            #pragma unroll 8
            for (int q = 0; q < CA; ++q) acc += assS[oi * CA + q] * HcS[q * 20 + c];
            v += acc;
        }
        out[(size_t)b * (KP * 20) + o] = v;
    }
}

extern "C" void kernel_launch(void* const* d_in, const int* in_sizes, int n_in,
                              void* d_out, int out_size, void* d_ws, size_t ws_size,
                              hipStream_t stream) {
    const float* features   = (const float*)d_in[0];
    const float* edge_attr  = (const float*)d_in[1];
    // d_in[2] = adj (unused by reference)
    const int*   edge_index = (const int*)d_in[3];
    const float* Wl1 = (const float*)d_in[4];
    const float* bl1 = (const float*)d_in[5];
    const float* Wr1 = (const float*)d_in[6];
    const float* br1 = (const float*)d_in[7];
    const float* Wl2 = (const float*)d_in[8];
    const float* bl2 = (const float*)d_in[9];
    const float* Wr2 = (const float*)d_in[10];
    const float* br2 = (const float*)d_in[11];
    const float* Wg1 = (const float*)d_in[12];
    const float* bg1 = (const float*)d_in[13];
    const float* Wrel = (const float*)d_in[14];
    const float* brel = (const float*)d_in[15];
    const float* Wroot = (const float*)d_in[16];
    const float* Wc0 = (const float*)d_in[17];
    const float* Wc1 = (const float*)d_in[18];
    const float* Wc2 = (const float*)d_in[19];
    const float* bc  = (const float*)d_in[20];
    float* out = (float*)d_out;

    int B = in_sizes[0] / (N * N);
    brain_fused<<<dim3(B), dim3(NT), 0, stream>>>(
        features, edge_attr, edge_index,
        Wl1, bl1, Wr1, br1, Wl2, bl2, Wr2, br2, Wg1, bg1,
        Wrel, brel, Wroot, Wc0, Wc1, Wc2, bc, out);
}